// Round 6
// baseline (566.017 us; speedup 1.0000x reference)
//
#include <hip/hip_runtime.h>
#include <hip/hip_bf16.h>

#define D 64

typedef __attribute__((ext_vector_type(8))) short bf16x8;
typedef __attribute__((ext_vector_type(4))) float f32x4;

__device__ __forceinline__ short f2bf(float x) {
    unsigned u = __float_as_uint(x);
    unsigned r = (u + 0x7fffu + ((u >> 16) & 1u)) >> 16;  // RNE
    return (short)r;
}
__device__ __forceinline__ float bf2f(unsigned short u) {
    return __uint_as_float((unsigned)u << 16);
}

// ---------------- int64-vs-int32 edge_index detection ----------------
__global__ void detect_kernel(const unsigned int* e32, int* flag) {
    __shared__ int nz;
    if (threadIdx.x == 0) nz = 0;
    __syncthreads();
    if (e32[2 * threadIdx.x + 1] != 0) nz = 1;
    __syncthreads();
    if (threadIdx.x == 0) *flag = (nz == 0) ? 1 : 0;
}

__device__ __forceinline__ int load_idx(const void* e, int is64, long long i) {
    if (is64) return (int)((const long long*)e)[i];
    return ((const int*)e)[i];
}

// ---------------- degree histogram ----------------
__global__ void deg_count_kernel(const void* edges, const int* flag, int* degi, int E) {
    int e = blockIdx.x * 256 + threadIdx.x;
    if (e >= E) return;
    int is64 = *flag;
    int dst = load_idx(edges, is64, (long long)E + e);
    atomicAdd(&degi[dst], 1);
}

__global__ void dinv_kernel(const int* degi, float* dinv, int n) {
    int v = blockIdx.x * 256 + threadIdx.x;
    if (v >= n) return;
    dinv[v] = rsqrtf((float)(degi[v] + 1));
}

// ---------------- exclusive scan ----------------
__global__ __launch_bounds__(1024) void scanA_kernel(const int* deg, int* offs, int* bsums, int n) {
    __shared__ int s[1024];
    int tid = threadIdx.x;
    int i = blockIdx.x * 1024 + tid;
    int v = (i < n) ? deg[i] : 0;
    s[tid] = v;
    __syncthreads();
    for (int d = 1; d < 1024; d <<= 1) {
        int t = (tid >= d) ? s[tid - d] : 0;
        __syncthreads();
        s[tid] += t;
        __syncthreads();
    }
    if (i < n) offs[i] = s[tid] - v;
    if (tid == 1023) bsums[blockIdx.x] = s[1023];
}

__global__ __launch_bounds__(1024) void scanB_kernel(int* bsums, int nb) {
    __shared__ int s[1024];
    int tid = threadIdx.x;
    int v = (tid < nb) ? bsums[tid] : 0;
    s[tid] = v;
    __syncthreads();
    for (int d = 1; d < 1024; d <<= 1) {
        int t = (tid >= d) ? s[tid - d] : 0;
        __syncthreads();
        s[tid] += t;
        __syncthreads();
    }
    if (tid < nb) bsums[tid] = s[tid] - v;
}

__global__ __launch_bounds__(1024) void scanC_kernel(int* offs, const int* bsums, int* fillptr,
                                                     int n, int E) {
    int i = blockIdx.x * 1024 + threadIdx.x;
    if (i < n) {
        int o = offs[i] + bsums[blockIdx.x];
        offs[i] = o;
        fillptr[i] = o;
    }
    if (i == 0) offs[n] = E;
}

// ---------------- CSR fill: src index only (4B scatter, no norms) ----------------
// Norms eliminated algebraically: messages are pre-scaled by dinv[src] in the
// matmul epilogue; agg multiplies the whole sum by dinv[dst] once.
__global__ void fill_kernel(const void* edges, const int* flag,
                            int* fillptr, int* srcs, int E) {
    int e = blockIdx.x * 256 + threadIdx.x;
    if (e >= E) return;
    int is64 = *flag;
    int s = load_idx(edges, is64, e);
    int d = load_idx(edges, is64, (long long)E + e);
    int pos = atomicAdd(&fillptr[d], 1);
    srcs[pos] = s;
}

// ---------------- fused (BN+ReLU) -> [n,64]@[64,64] MFMA matmul ----------------
// One wave per 16-row tile; A from global (fp32), BN+ReLU in fp32, cvt bf16,
// 8x mfma_f32_16x16x32_bf16. Epilogue scales row r by dinv[r] and writes bf16
// messages T' = dinv[r]*h[r] — agg becomes a pure gather-sum.
// Layouts (HW-verified): A[m=lane&15][k=quad*8+j]; B[k=quad*8+j][n=lane&15];
// C col=lane&15, row=quad*4+reg.
__global__ __launch_bounds__(256) void mm_bn_kernel(
    const float* __restrict__ X, const float* __restrict__ W,
    const float* __restrict__ stats, const float* __restrict__ gamma,
    const float* __restrict__ beta, int use_bn, float inv_n,
    const float* __restrict__ dinv,
    unsigned short* __restrict__ Y, int n) {
    int lane = threadIdx.x & 63;
    int m = lane & 15;
    int quad = lane >> 4;

    float sc[16], sh[16];
#pragma unroll
    for (int s = 0; s < 2; s++) {
#pragma unroll
        for (int j = 0; j < 8; j++) {
            float scale = 1.f, shift = 0.f;
            if (use_bn) {
                int f = s * 32 + quad * 8 + j;
                float mean = stats[f] * inv_n;
                float var = stats[64 + f] * inv_n - mean * mean;
                float rs = rsqrtf(var + 1e-5f);
                scale = rs * gamma[f];
                shift = beta[f] - mean * scale;
            }
            sc[s * 8 + j] = scale;
            sh[s * 8 + j] = shift;
        }
    }

    bf16x8 bfrag[4][2];
#pragma unroll
    for (int nt = 0; nt < 4; nt++) {
#pragma unroll
        for (int s = 0; s < 2; s++) {
#pragma unroll
            for (int j = 0; j < 8; j++) {
                int k = s * 32 + quad * 8 + j;
                bfrag[nt][s][j] = f2bf(W[k * 64 + nt * 16 + m]);
            }
        }
    }

    int wave = blockIdx.x * 4 + (threadIdx.x >> 6);
    int nwaves = gridDim.x * 4;
    int ntiles = (n + 15) >> 4;
    const f32x4 zero = {0.f, 0.f, 0.f, 0.f};

    for (int t = wave; t < ntiles; t += nwaves) {
        int r = t * 16 + m;
        if (r >= n) r = n - 1;  // redundant load; stores are guarded
        const float* xr = X + (long long)r * 64;
        f32x4 a0 = *(const f32x4*)(xr + quad * 8);
        f32x4 a1 = *(const f32x4*)(xr + quad * 8 + 4);
        f32x4 a2 = *(const f32x4*)(xr + 32 + quad * 8);
        f32x4 a3 = *(const f32x4*)(xr + 32 + quad * 8 + 4);

        float av[16];
#pragma unroll
        for (int j = 0; j < 4; j++) {
            av[j] = a0[j];
            av[4 + j] = a1[j];
            av[8 + j] = a2[j];
            av[12 + j] = a3[j];
        }
        bf16x8 A0, A1;
#pragma unroll
        for (int j = 0; j < 8; j++) {
            float v0 = av[j] * sc[j] + sh[j];
            float v1 = av[8 + j] * sc[8 + j] + sh[8 + j];
            if (use_bn) {
                v0 = fmaxf(v0, 0.f);
                v1 = fmaxf(v1, 0.f);
            }
            A0[j] = f2bf(v0);
            A1[j] = f2bf(v1);
        }

        f32x4 acc[4];
#pragma unroll
        for (int nt = 0; nt < 4; nt++) {
            acc[nt] = __builtin_amdgcn_mfma_f32_16x16x32_bf16(A0, bfrag[nt][0], zero, 0, 0, 0);
            acc[nt] = __builtin_amdgcn_mfma_f32_16x16x32_bf16(A1, bfrag[nt][1], acc[nt], 0, 0, 0);
        }

        int row0 = t * 16 + quad * 4;
        float dv[4];
#pragma unroll
        for (int i = 0; i < 4; i++) {
            int rr = row0 + i;
            dv[i] = (rr < n) ? dinv[rr] : 0.f;
        }
#pragma unroll
        for (int nt = 0; nt < 4; nt++) {
#pragma unroll
            for (int i = 0; i < 4; i++) {
                int rr = row0 + i;
                if (rr < n)
                    Y[(long long)rr * 64 + nt * 16 + m] = (unsigned short)f2bf(acc[nt][i] * dv[i]);
            }
        }
    }
}

// ---------------- aggregation: pure gather-sum + fused BN stats ----------------
// out[v] = dinv[v] * (T'[v] + sum_{s in N(v)} T'[s]) + bias.  lane == feature.
// Grid-stride (2560 blocks); per-lane s/q partials -> LDS -> 128 atomics/block.
__global__ __launch_bounds__(256) void agg_kernel(const unsigned short* __restrict__ T,
                                                  const int* __restrict__ offs,
                                                  const int* __restrict__ srcs,
                                                  const float* __restrict__ dinv,
                                                  const float* __restrict__ bias,
                                                  float* __restrict__ out,
                                                  float* __restrict__ stats, int do_stats,
                                                  int n) {
    int lane = threadIdx.x & 63;
    int w = threadIdx.x >> 6;
    float bi = bias[lane];
    float s_acc = 0.f, q_acc = 0.f;

    for (int v = blockIdx.x * 4 + w; v < n; v += gridDim.x * 4) {
        float acc = bf2f(T[(long long)v * D + lane]);  // self-loop (pre-scaled)
        int j = offs[v], j1 = offs[v + 1];
        for (; j + 8 <= j1; j += 8) {
            int s0 = srcs[j + 0], s1 = srcs[j + 1], s2 = srcs[j + 2], s3 = srcs[j + 3];
            int s4 = srcs[j + 4], s5 = srcs[j + 5], s6 = srcs[j + 6], s7 = srcs[j + 7];
            float t0 = bf2f(T[(long long)s0 * D + lane]);
            float t1 = bf2f(T[(long long)s1 * D + lane]);
            float t2 = bf2f(T[(long long)s2 * D + lane]);
            float t3 = bf2f(T[(long long)s3 * D + lane]);
            float t4 = bf2f(T[(long long)s4 * D + lane]);
            float t5 = bf2f(T[(long long)s5 * D + lane]);
            float t6 = bf2f(T[(long long)s6 * D + lane]);
            float t7 = bf2f(T[(long long)s7 * D + lane]);
            acc += ((t0 + t1) + (t2 + t3)) + ((t4 + t5) + (t6 + t7));
        }
        for (; j + 4 <= j1; j += 4) {
            int s0 = srcs[j + 0], s1 = srcs[j + 1], s2 = srcs[j + 2], s3 = srcs[j + 3];
            float t0 = bf2f(T[(long long)s0 * D + lane]);
            float t1 = bf2f(T[(long long)s1 * D + lane]);
            float t2 = bf2f(T[(long long)s2 * D + lane]);
            float t3 = bf2f(T[(long long)s3 * D + lane]);
            acc += (t0 + t1) + (t2 + t3);
        }
        for (; j < j1; j++) acc += bf2f(T[(long long)srcs[j] * D + lane]);

        float val = dinv[v] * acc + bi;
        out[(long long)v * D + lane] = val;
        s_acc += val;
        q_acc += val * val;
    }

    if (do_stats) {
        __shared__ float ls[256], lq[256];
        ls[threadIdx.x] = s_acc;
        lq[threadIdx.x] = q_acc;
        __syncthreads();
        if (w == 0) {
            float s = ls[lane] + ls[64 + lane] + ls[128 + lane] + ls[192 + lane];
            float q = lq[lane] + lq[64 + lane] + lq[128 + lane] + lq[192 + lane];
            atomicAdd(&stats[lane], s);
            atomicAdd(&stats[64 + lane], q);
        }
    }
}

// ---------------- host ----------------
extern "C" void kernel_launch(void* const* d_in, const int* in_sizes, int n_in,
                              void* d_out, int out_size, void* d_ws, size_t ws_size,
                              hipStream_t stream) {
    const float* x = (const float*)d_in[0];
    const void* edges = d_in[1];
    const float* W1 = (const float*)d_in[3];
    const float* b1 = (const float*)d_in[4];
    const float* gamma1 = (const float*)d_in[5];
    const float* beta1 = (const float*)d_in[6];
    const float* W2 = (const float*)d_in[7];
    const float* b2 = (const float*)d_in[8];
    const float* gamma2 = (const float*)d_in[9];
    const float* beta2 = (const float*)d_in[10];
    const float* W3 = (const float*)d_in[11];
    const float* b3 = (const float*)d_in[12];

    const int N = in_sizes[0] / D;
    const int E = in_sizes[1] / 2;
    const float inv_n = 1.f / (float)N;

    char* ws = (char*)d_ws;
    size_t off = 0;
    auto alloc = [&](size_t bytes) -> void* {
        void* p = ws + off;
        off = (off + bytes + 255) & ~(size_t)255;
        return p;
    };
    float* dinv  = (float*)alloc((size_t)N * 4);
    int*   degi  = (int*)  alloc((size_t)N * 4);
    int*   offs  = (int*)  alloc((size_t)(N + 1) * 4);
    int*   fillp = (int*)  alloc((size_t)N * 4);
    int*   srcs  = (int*)  alloc((size_t)E * 4);
    int*   bsums = (int*)  alloc(1024 * 4);
    int*   flag  = (int*)  alloc(4);
    float* stats = (float*)alloc(128 * 4);
    unsigned short* bufA = (unsigned short*)alloc((size_t)N * D * 2);  // bf16 messages
    float* hbuf  = (float*)d_out;  // fp32 ping-pong; fully overwritten each layer

    const int eb = (E + 255) / 256;
    const int nb256 = (N + 255) / 256;
    const int nb1024 = (N + 1023) / 1024;
    const int NBAGG = 2560;

    // ---- build CSR (once, reused 3x) ----
    hipMemsetAsync(degi, 0, (size_t)N * 4, stream);
    detect_kernel<<<1, 256, 0, stream>>>((const unsigned int*)edges, flag);
    deg_count_kernel<<<eb, 256, 0, stream>>>(edges, flag, degi, E);
    dinv_kernel<<<nb256, 256, 0, stream>>>(degi, dinv, N);
    scanA_kernel<<<nb1024, 1024, 0, stream>>>(degi, offs, bsums, N);
    scanB_kernel<<<1, 1024, 0, stream>>>(bsums, nb1024);
    scanC_kernel<<<nb1024, 1024, 0, stream>>>(offs, bsums, fillp, N, E);
    fill_kernel<<<eb, 256, 0, stream>>>(edges, flag, fillp, srcs, E);

    // ---- layer 1 ----
    hipMemsetAsync(stats, 0, 128 * 4, stream);
    mm_bn_kernel<<<512, 256, 0, stream>>>(x, W1, nullptr, nullptr, nullptr, 0, inv_n, dinv, bufA, N);
    agg_kernel<<<NBAGG, 256, 0, stream>>>(bufA, offs, srcs, dinv, b1, hbuf, stats, 1, N);

    // ---- layer 2 (BN1+ReLU fused into matmul A-load) ----
    mm_bn_kernel<<<512, 256, 0, stream>>>(hbuf, W2, stats, gamma1, beta1, 1, inv_n, dinv, bufA, N);
    hipMemsetAsync(stats, 0, 128 * 4, stream);
    agg_kernel<<<NBAGG, 256, 0, stream>>>(bufA, offs, srcs, dinv, b2, hbuf, stats, 1, N);

    // ---- layer 3 (BN2+ReLU fused; no BN after) ----
    mm_bn_kernel<<<512, 256, 0, stream>>>(hbuf, W3, stats, gamma2, beta2, 1, inv_n, dinv, bufA, N);
    agg_kernel<<<NBAGG, 256, 0, stream>>>(bufA, offs, srcs, dinv, b3, (float*)d_out, stats, 0, N);
}

// Round 7
// 484.137 us; speedup vs baseline: 1.1691x; 1.1691x over previous
//
#include <hip/hip_runtime.h>
#include <hip/hip_bf16.h>

#define D 64

typedef __attribute__((ext_vector_type(8))) short bf16x8;
typedef __attribute__((ext_vector_type(4))) float f32x4;

__device__ __forceinline__ short f2bf(float x) {
    unsigned u = __float_as_uint(x);
    unsigned r = (u + 0x7fffu + ((u >> 16) & 1u)) >> 16;  // RNE
    return (short)r;
}
__device__ __forceinline__ float bf2f(unsigned short u) {
    return __uint_as_float((unsigned)u << 16);
}

// ---------------- int64-vs-int32 edge_index detection ----------------
__global__ void detect_kernel(const unsigned int* e32, int* flag) {
    __shared__ int nz;
    if (threadIdx.x == 0) nz = 0;
    __syncthreads();
    if (e32[2 * threadIdx.x + 1] != 0) nz = 1;
    __syncthreads();
    if (threadIdx.x == 0) *flag = (nz == 0) ? 1 : 0;
}

__device__ __forceinline__ int load_idx(const void* e, int is64, long long i) {
    if (is64) return (int)((const long long*)e)[i];
    return ((const int*)e)[i];
}

// ---------------- degree histogram ----------------
__global__ void deg_count_kernel(const void* edges, const int* flag, int* degi, int E) {
    int e = blockIdx.x * 256 + threadIdx.x;
    if (e >= E) return;
    int is64 = *flag;
    int dst = load_idx(edges, is64, (long long)E + e);
    atomicAdd(&degi[dst], 1);
}

__global__ void dinv_kernel(const int* degi, float* dinv, int n) {
    int v = blockIdx.x * 256 + threadIdx.x;
    if (v >= n) return;
    dinv[v] = rsqrtf((float)(degi[v] + 1));
}

// ---------------- exclusive scan ----------------
__global__ __launch_bounds__(1024) void scanA_kernel(const int* deg, int* offs, int* bsums, int n) {
    __shared__ int s[1024];
    int tid = threadIdx.x;
    int i = blockIdx.x * 1024 + tid;
    int v = (i < n) ? deg[i] : 0;
    s[tid] = v;
    __syncthreads();
    for (int d = 1; d < 1024; d <<= 1) {
        int t = (tid >= d) ? s[tid - d] : 0;
        __syncthreads();
        s[tid] += t;
        __syncthreads();
    }
    if (i < n) offs[i] = s[tid] - v;
    if (tid == 1023) bsums[blockIdx.x] = s[1023];
}

__global__ __launch_bounds__(1024) void scanB_kernel(int* bsums, int nb) {
    __shared__ int s[1024];
    int tid = threadIdx.x;
    int v = (tid < nb) ? bsums[tid] : 0;
    s[tid] = v;
    __syncthreads();
    for (int d = 1; d < 1024; d <<= 1) {
        int t = (tid >= d) ? s[tid - d] : 0;
        __syncthreads();
        s[tid] += t;
        __syncthreads();
    }
    if (tid < nb) bsums[tid] = s[tid] - v;
}

__global__ __launch_bounds__(1024) void scanC_kernel(int* offs, const int* bsums, int* fillptr,
                                                     int n, int E) {
    int i = blockIdx.x * 1024 + threadIdx.x;
    if (i < n) {
        int o = offs[i] + bsums[blockIdx.x];
        offs[i] = o;
        fillptr[i] = o;
    }
    if (i == 0) offs[n] = E;
}

// ---------------- CSR fill: src index only (4B scatter, no norms) ----------------
__global__ void fill_kernel(const void* edges, const int* flag,
                            int* fillptr, int* srcs, int E) {
    int e = blockIdx.x * 256 + threadIdx.x;
    if (e >= E) return;
    int is64 = *flag;
    int s = load_idx(edges, is64, e);
    int d = load_idx(edges, is64, (long long)E + e);
    int pos = atomicAdd(&fillptr[d], 1);
    srcs[pos] = s;
}

// ---------------- fused (BN+ReLU) -> [n,64]@[64,64] MFMA matmul ----------------
// One wave per 16-row tile; BN+ReLU in fp32 on load, cvt bf16, 8x
// mfma_f32_16x16x32_bf16; epilogue scales row r by dinv[r], writes bf16
// messages T' = dinv[r]*h[r].
__global__ __launch_bounds__(256) void mm_bn_kernel(
    const float* __restrict__ X, const float* __restrict__ W,
    const float* __restrict__ stats, const float* __restrict__ gamma,
    const float* __restrict__ beta, int use_bn, float inv_n,
    const float* __restrict__ dinv,
    unsigned short* __restrict__ Y, int n) {
    int lane = threadIdx.x & 63;
    int m = lane & 15;
    int quad = lane >> 4;

    float sc[16], sh[16];
#pragma unroll
    for (int s = 0; s < 2; s++) {
#pragma unroll
        for (int j = 0; j < 8; j++) {
            float scale = 1.f, shift = 0.f;
            if (use_bn) {
                int f = s * 32 + quad * 8 + j;
                float mean = stats[f] * inv_n;
                float var = stats[64 + f] * inv_n - mean * mean;
                float rs = rsqrtf(var + 1e-5f);
                scale = rs * gamma[f];
                shift = beta[f] - mean * scale;
            }
            sc[s * 8 + j] = scale;
            sh[s * 8 + j] = shift;
        }
    }

    bf16x8 bfrag[4][2];
#pragma unroll
    for (int nt = 0; nt < 4; nt++) {
#pragma unroll
        for (int s = 0; s < 2; s++) {
#pragma unroll
            for (int j = 0; j < 8; j++) {
                int k = s * 32 + quad * 8 + j;
                bfrag[nt][s][j] = f2bf(W[k * 64 + nt * 16 + m]);
            }
        }
    }

    int wave = blockIdx.x * 4 + (threadIdx.x >> 6);
    int nwaves = gridDim.x * 4;
    int ntiles = (n + 15) >> 4;
    const f32x4 zero = {0.f, 0.f, 0.f, 0.f};

    for (int t = wave; t < ntiles; t += nwaves) {
        int r = t * 16 + m;
        if (r >= n) r = n - 1;  // redundant load; stores are guarded
        const float* xr = X + (long long)r * 64;
        f32x4 a0 = *(const f32x4*)(xr + quad * 8);
        f32x4 a1 = *(const f32x4*)(xr + quad * 8 + 4);
        f32x4 a2 = *(const f32x4*)(xr + 32 + quad * 8);
        f32x4 a3 = *(const f32x4*)(xr + 32 + quad * 8 + 4);

        float av[16];
#pragma unroll
        for (int j = 0; j < 4; j++) {
            av[j] = a0[j];
            av[4 + j] = a1[j];
            av[8 + j] = a2[j];
            av[12 + j] = a3[j];
        }
        bf16x8 A0, A1;
#pragma unroll
        for (int j = 0; j < 8; j++) {
            float v0 = av[j] * sc[j] + sh[j];
            float v1 = av[8 + j] * sc[8 + j] + sh[8 + j];
            if (use_bn) {
                v0 = fmaxf(v0, 0.f);
                v1 = fmaxf(v1, 0.f);
            }
            A0[j] = f2bf(v0);
            A1[j] = f2bf(v1);
        }

        f32x4 acc[4];
#pragma unroll
        for (int nt = 0; nt < 4; nt++) {
            acc[nt] = __builtin_amdgcn_mfma_f32_16x16x32_bf16(A0, bfrag[nt][0], zero, 0, 0, 0);
            acc[nt] = __builtin_amdgcn_mfma_f32_16x16x32_bf16(A1, bfrag[nt][1], acc[nt], 0, 0, 0);
        }

        int row0 = t * 16 + quad * 4;
        float dv[4];
#pragma unroll
        for (int i = 0; i < 4; i++) {
            int rr = row0 + i;
            dv[i] = (rr < n) ? dinv[rr] : 0.f;
        }
#pragma unroll
        for (int nt = 0; nt < 4; nt++) {
#pragma unroll
            for (int i = 0; i < 4; i++) {
                int rr = row0 + i;
                if (rr < n)
                    Y[(long long)rr * 64 + nt * 16 + m] = (unsigned short)f2bf(acc[nt][i] * dv[i]);
            }
        }
    }
}

// ---------------- aggregation: one wave per dst (block churn = MLP), ----------
// pure gather-sum of pre-scaled messages; edges in masked batches of 8 so even
// tail edges have 8 gathers in flight. out[v] = dinv[v]*sum + bias.
__global__ __launch_bounds__(256) void agg_kernel(const unsigned short* __restrict__ T,
                                                  const int* __restrict__ offs,
                                                  const int* __restrict__ srcs,
                                                  const float* __restrict__ dinv,
                                                  const float* __restrict__ bias,
                                                  float* __restrict__ out, int n) {
    int v = blockIdx.x * 4 + (threadIdx.x >> 6);
    if (v >= n) return;
    int lane = threadIdx.x & 63;
    float acc = bf2f(T[(long long)v * D + lane]);  // self-loop (pre-scaled)
    int j0 = offs[v], j1 = offs[v + 1];
    for (int j = j0; j < j1; j += 8) {
        int sidx[8];
        float wgt[8];
#pragma unroll
        for (int u = 0; u < 8; u++) {
            int jj = j + u;
            int jc = jj < j1 ? jj : j1 - 1;  // clamp (j < j1 inside loop)
            sidx[u] = srcs[jc];
            wgt[u] = (jj < j1) ? 1.f : 0.f;
        }
        float t[8];
#pragma unroll
        for (int u = 0; u < 8; u++) t[u] = bf2f(T[(long long)sidx[u] * D + lane]);
        float p0 = wgt[0] * t[0] + wgt[1] * t[1];
        float p1 = wgt[2] * t[2] + wgt[3] * t[3];
        float p2 = wgt[4] * t[4] + wgt[5] * t[5];
        float p3 = wgt[6] * t[6] + wgt[7] * t[7];
        acc += (p0 + p1) + (p2 + p3);
    }
    out[(long long)v * D + lane] = dinv[v] * acc + bias[lane];
}

// ---------------- batchnorm stats ----------------
__global__ __launch_bounds__(256) void bnstats_kernel(const float* __restrict__ H,
                                                      float* __restrict__ stats, int n) {
    int f = threadIdx.x & 63;
    int r = threadIdx.x >> 6;
    float s = 0.f, q = 0.f;
    for (int node = blockIdx.x * 4 + r; node < n; node += gridDim.x * 4) {
        float x = H[(long long)node * D + f];
        s += x;
        q += x * x;
    }
    __shared__ float ls[256], lq[256];
    ls[threadIdx.x] = s;
    lq[threadIdx.x] = q;
    __syncthreads();
    if (r == 0) {
        s = ls[f] + ls[64 + f] + ls[128 + f] + ls[192 + f];
        q = lq[f] + lq[64 + f] + lq[128 + f] + lq[192 + f];
        atomicAdd(&stats[f], s);
        atomicAdd(&stats[64 + f], q);
    }
}

// ---------------- host ----------------
extern "C" void kernel_launch(void* const* d_in, const int* in_sizes, int n_in,
                              void* d_out, int out_size, void* d_ws, size_t ws_size,
                              hipStream_t stream) {
    const float* x = (const float*)d_in[0];
    const void* edges = d_in[1];
    const float* W1 = (const float*)d_in[3];
    const float* b1 = (const float*)d_in[4];
    const float* gamma1 = (const float*)d_in[5];
    const float* beta1 = (const float*)d_in[6];
    const float* W2 = (const float*)d_in[7];
    const float* b2 = (const float*)d_in[8];
    const float* gamma2 = (const float*)d_in[9];
    const float* beta2 = (const float*)d_in[10];
    const float* W3 = (const float*)d_in[11];
    const float* b3 = (const float*)d_in[12];

    const int N = in_sizes[0] / D;
    const int E = in_sizes[1] / 2;
    const float inv_n = 1.f / (float)N;

    char* ws = (char*)d_ws;
    size_t off = 0;
    auto alloc = [&](size_t bytes) -> void* {
        void* p = ws + off;
        off = (off + bytes + 255) & ~(size_t)255;
        return p;
    };
    float* dinv  = (float*)alloc((size_t)N * 4);
    int*   degi  = (int*)  alloc((size_t)N * 4);
    int*   offs  = (int*)  alloc((size_t)(N + 1) * 4);
    int*   fillp = (int*)  alloc((size_t)N * 4);
    int*   srcs  = (int*)  alloc((size_t)E * 4);
    int*   bsums = (int*)  alloc(1024 * 4);
    int*   flag  = (int*)  alloc(4);
    float* stats = (float*)alloc(128 * 4);
    unsigned short* bufA = (unsigned short*)alloc((size_t)N * D * 2);  // bf16 messages
    float* hbuf  = (float*)d_out;  // fp32 ping-pong; fully overwritten each layer

    const int eb = (E + 255) / 256;
    const int nb256 = (N + 255) / 256;
    const int nb1024 = (N + 1023) / 1024;
    const int aggb = (N + 3) / 4;

    // ---- build CSR (once, reused 3x) ----
    hipMemsetAsync(degi, 0, (size_t)N * 4, stream);
    detect_kernel<<<1, 256, 0, stream>>>((const unsigned int*)edges, flag);
    deg_count_kernel<<<eb, 256, 0, stream>>>(edges, flag, degi, E);
    dinv_kernel<<<nb256, 256, 0, stream>>>(degi, dinv, N);
    scanA_kernel<<<nb1024, 1024, 0, stream>>>(degi, offs, bsums, N);
    scanB_kernel<<<1, 1024, 0, stream>>>(bsums, nb1024);
    scanC_kernel<<<nb1024, 1024, 0, stream>>>(offs, bsums, fillp, N, E);
    fill_kernel<<<eb, 256, 0, stream>>>(edges, flag, fillp, srcs, E);

    // ---- layer 1 ----
    mm_bn_kernel<<<512, 256, 0, stream>>>(x, W1, nullptr, nullptr, nullptr, 0, inv_n, dinv, bufA, N);
    agg_kernel<<<aggb, 256, 0, stream>>>(bufA, offs, srcs, dinv, b1, hbuf, N);
    hipMemsetAsync(stats, 0, 128 * 4, stream);
    bnstats_kernel<<<512, 256, 0, stream>>>(hbuf, stats, N);

    // ---- layer 2 (BN1+ReLU fused into matmul A-load) ----
    mm_bn_kernel<<<512, 256, 0, stream>>>(hbuf, W2, stats, gamma1, beta1, 1, inv_n, dinv, bufA, N);
    agg_kernel<<<aggb, 256, 0, stream>>>(bufA, offs, srcs, dinv, b2, hbuf, N);
    hipMemsetAsync(stats, 0, 128 * 4, stream);
    bnstats_kernel<<<512, 256, 0, stream>>>(hbuf, stats, N);

    // ---- layer 3 (BN2+ReLU fused; no BN after) ----
    mm_bn_kernel<<<512, 256, 0, stream>>>(hbuf, W3, stats, gamma2, beta2, 1, inv_n, dinv, bufA, N);
    agg_kernel<<<aggb, 256, 0, stream>>>(bufA, offs, srcs, dinv, b3, (float*)d_out, N);
}